// Round 8
// baseline (650.593 us; speedup 1.0000x reference)
//
#include <hip/hip_runtime.h>
#include <cstdint>
#include <cstddef>

typedef _Float16 half8 __attribute__((ext_vector_type(8)));
typedef _Float16 half4 __attribute__((ext_vector_type(4)));
typedef float floatx4 __attribute__((ext_vector_type(4)));

#define BATCH 256
#define NCHK 512
#define NVAR 1024
#define EDGE 3072

// ---- check MLP tiling ----
#define KC    96
#define NT1C  26     // hidden 388 -> 416 -> 26 col-tiles of 16
#define KS1C  3      // GEMM1 K = 96 -> 3 chunks of 32
#define NT2C  6      // out 96 -> 6 tiles of 16 (3 b128 pairs)
// ---- var MLP tiling ----
#define NT1V  13     // hidden 196 -> 208 -> 13 col-tiles of 16
#define KS1V  2      // GEMM1 K 49 -> 64 -> 2 chunks of 32
#define NT2V  4      // out 49 -> 64 -> 4 tiles of 16 (2 b128 pairs)

__device__ __forceinline__ float gelu_f(float x) {
  // exact gelu via A&S 7.1.26 erf approx, |err(erf)| < 1.5e-7 (table builder only)
  float ax = fabsf(x) * 0.70710678118654752440f;
  float t  = 1.0f / fmaf(0.3275911f, ax, 1.0f);
  float p  = t * (0.254829592f + t * (-0.284496736f + t * (1.421413741f +
             t * (-1.453152027f + t * 1.061405429f))));
  float e  = __expf(-ax * ax);
  float erfv = fmaf(-p, e, 1.0f);
  float s  = copysignf(erfv, x);
  float hx = 0.5f * x;
  return fmaf(hx, s, hx);
}

// PWL gelu: 1024 segments over [-8,8], node+slope in LDS (float2, ds_read_b64).
// |err| <= w^2/8 * max|gelu''| = (1/64)^2/8 * 0.8 ~ 2.4e-5 absolute.
__device__ __forceinline__ float gelu_lut(const float2* __restrict__ tab, float x) {
  float t  = fmaf(x, 64.0f, 512.0f);
  float tc = fminf(fmaxf(t, 0.0f), 1023.0f);
  float tf = __builtin_truncf(tc);
  float fr = tc - tf;
  int idx  = (int)tf;
  float2 ns = tab[idx];
  float h  = fmaf(fr, ns.y, ns.x);
  return fmaf(fmaxf(t - tc, 0.0f), 0.015625f, h);
}

#define BUILD_TAB(tab)                                            \
  for (int k_ = threadIdx.x; k_ < 1024; k_ += 256) {              \
    float x_  = (k_ - 512) * 0.015625f;                           \
    float y0_ = gelu_f(x_);                                       \
    float y1_ = gelu_f(x_ + 0.015625f);                           \
    tab[k_] = make_float2(y0_, y1_ - y0_);                        \
  }                                                               \
  __syncthreads();

__device__ __forceinline__ half4 lo4(half8 v) {
  return __builtin_shufflevector(v, v, 0, 1, 2, 3);
}
__device__ __forceinline__ half4 hi4(half8 v) {
  return __builtin_shufflevector(v, v, 4, 5, 6, 7);
}

// W1 packs: K32 A-operand fragments (16x16x32). W2 packs: K16 A-operand
// fragments in nt-PAIRS (b128 loads). Bias combos bwp/bwm = b1 +/- w96.
__global__ void pack_kernel(const float* __restrict__ cW1, const float* __restrict__ cb1,
                            const float* __restrict__ cW2, const float* __restrict__ cb2,
                            const float* __restrict__ vW1, const float* __restrict__ vb1,
                            const float* __restrict__ vW2, const float* __restrict__ vb2,
                            _Float16* __restrict__ w1c, _Float16* __restrict__ w2c,
                            _Float16* __restrict__ w1v, _Float16* __restrict__ w2v,
                            float* __restrict__ bwp, float* __restrict__ bwm,
                            float* __restrict__ b2c, float* __restrict__ b1v,
                            float* __restrict__ b2v)
{
  int id = blockIdx.x * 256 + threadIdx.x;
  const int S0 = KS1C * NT1C * 64;   // 4992  (half8)
  const int S1 = NT1C * 3 * 64;      // 4992  (half8 = paired half4)
  const int S2 = KS1V * NT1V * 64;   // 1664  (half8)
  const int S3 = NT1V * 2 * 64;      // 1664  (half8 = paired half4)
  if (id < S0) {
    int s = id / (NT1C * 64), rem = id % (NT1C * 64), nt = rem / 64, l = rem % 64;
    int q = l >> 4, n = nt * 16 + (l & 15);
    half8 v;
    #pragma unroll
    for (int j = 0; j < 8; ++j) {
      int k = s * 32 + q * 8 + j;
      float x = (n < 388) ? cW1[k * 388 + n] : 0.0f;
      v[j] = (_Float16)x;
    }
    *(half8*)(w1c + (size_t)id * 8) = v;
    return;
  }
  id -= S0;
  if (id < S1) {
    int ht = id / (3 * 64), rem = id % (3 * 64), np = rem / 64, l = rem % 64;
    int q = l >> 4, c = l & 15;
    half8 v;
    #pragma unroll
    for (int j = 0; j < 8; ++j) {
      int k = ht * 16 + q * 4 + (j & 3);
      int n = (2 * np + (j >> 2)) * 16 + c;
      float x = (k < 388) ? cW2[k * 96 + n] : 0.0f;
      v[j] = (_Float16)x;
    }
    *(half8*)(w2c + (size_t)id * 8) = v;
    return;
  }
  id -= S1;
  if (id < S2) {
    int s = id / (NT1V * 64), rem = id % (NT1V * 64), nt = rem / 64, l = rem % 64;
    int q = l >> 4, n = nt * 16 + (l & 15);
    half8 v;
    #pragma unroll
    for (int j = 0; j < 8; ++j) {
      int k = s * 32 + q * 8 + j;                        // row 48 = prior row
      float x = (k < 49 && n < 196) ? vW1[k * 196 + n] : 0.0f;
      v[j] = (_Float16)x;
    }
    *(half8*)(w1v + (size_t)id * 8) = v;
    return;
  }
  id -= S2;
  if (id < S3) {
    int ht = id / (2 * 64), rem = id % (2 * 64), np = rem / 64, l = rem % 64;
    int q = l >> 4, c = l & 15;
    half8 v;
    #pragma unroll
    for (int j = 0; j < 8; ++j) {
      int k = ht * 16 + q * 4 + (j & 3);
      int n = (2 * np + (j >> 2)) * 16 + c;
      float x = (k < 196 && n < 49) ? vW2[k * 49 + n] : 0.0f;
      v[j] = (_Float16)x;
    }
    *(half8*)(w2v + (size_t)id * 8) = v;
    return;
  }
  id -= S3;
  if (id < 416) {
    float b = (id < 388) ? cb1[id] : 0.0f;
    float wv = (id < 388) ? cW1[96 * 388 + id] : 0.0f;
    bwp[id] = b + wv;
    return;
  }
  id -= 416;
  if (id < 416) {
    float b = (id < 388) ? cb1[id] : 0.0f;
    float wv = (id < 388) ? cW1[96 * 388 + id] : 0.0f;
    bwm[id] = b - wv;
    return;
  }
  id -= 416;
  if (id < 96)  { b2c[id]  = cb2[id]; return; }
  id -= 96;
  if (id < 208) { b1v[id]  = (id < 196) ? vb1[id] : 0.0f; return; }
  id -= 208;
  if (id < 64)  { b2v[id]  = (id < 49) ? vb2[id] : 0.0f; return; }
}

__global__ void init_kernel(const int* __restrict__ perm, const float* __restrict__ prior,
                            _Float16* __restrict__ Mc)
{
  int t = blockIdx.x * 256 + threadIdx.x;   // t < BATCH*EDGE
  int b = t / EDGE, k = t - b * EDGE;
  int e = perm[k];
  _Float16* dst = Mc + ((size_t)b * EDGE + e) * 16;
  half8 z  = {0,0,0,0,0,0,0,0};
  half8 z0 = z;
  z0[0] = (_Float16)prior[k / 3];
  *(half8*)dst = z0;
  *(half8*)(dst + 8) = z;
}

// one ht-step of the check MLP for TWO row-groups (rg=2 amortizes the 8-load
// set over 2x MFMA+gelu work: weight L1/L2 traffic per dispatch HALVES —
// round-7 analysis: 23 TB/s of redundant weight refetch was the limiter)
#define CSTEP(WA0, WA1, WA2, WP0, WP1, WP2, WI0, WI1)                                    \
  {                                                                                      \
    floatx4 a0 = WI0, a1 = WI1;                                                          \
    a0 = __builtin_amdgcn_mfma_f32_16x16x32_f16(WA0, mb[0][0], a0, 0, 0, 0);             \
    a1 = __builtin_amdgcn_mfma_f32_16x16x32_f16(WA0, mb[1][0], a1, 0, 0, 0);             \
    a0 = __builtin_amdgcn_mfma_f32_16x16x32_f16(WA1, mb[0][1], a0, 0, 0, 0);             \
    a1 = __builtin_amdgcn_mfma_f32_16x16x32_f16(WA1, mb[1][1], a1, 0, 0, 0);             \
    a0 = __builtin_amdgcn_mfma_f32_16x16x32_f16(WA2, mb[0][2], a0, 0, 0, 0);             \
    a1 = __builtin_amdgcn_mfma_f32_16x16x32_f16(WA2, mb[1][2], a1, 0, 0, 0);             \
    half4 h0, h1;                                                                        \
    _Pragma("unroll")                                                                    \
    for (int r = 0; r < 4; ++r) h0[r] = (_Float16)gelu_lut(tab, a0[r]);                  \
    _Pragma("unroll")                                                                    \
    for (int r = 0; r < 4; ++r) h1[r] = (_Float16)gelu_lut(tab, a1[r]);                  \
    acc2[0][0] = __builtin_amdgcn_mfma_f32_16x16x16f16(lo4(WP0), h0, acc2[0][0], 0,0,0); \
    acc2[1][0] = __builtin_amdgcn_mfma_f32_16x16x16f16(lo4(WP0), h1, acc2[1][0], 0,0,0); \
    acc2[0][1] = __builtin_amdgcn_mfma_f32_16x16x16f16(hi4(WP0), h0, acc2[0][1], 0,0,0); \
    acc2[1][1] = __builtin_amdgcn_mfma_f32_16x16x16f16(hi4(WP0), h1, acc2[1][1], 0,0,0); \
    acc2[0][2] = __builtin_amdgcn_mfma_f32_16x16x16f16(lo4(WP1), h0, acc2[0][2], 0,0,0); \
    acc2[1][2] = __builtin_amdgcn_mfma_f32_16x16x16f16(lo4(WP1), h1, acc2[1][2], 0,0,0); \
    acc2[0][3] = __builtin_amdgcn_mfma_f32_16x16x16f16(hi4(WP1), h0, acc2[0][3], 0,0,0); \
    acc2[1][3] = __builtin_amdgcn_mfma_f32_16x16x16f16(hi4(WP1), h1, acc2[1][3], 0,0,0); \
    acc2[0][4] = __builtin_amdgcn_mfma_f32_16x16x16f16(lo4(WP2), h0, acc2[0][4], 0,0,0); \
    acc2[1][4] = __builtin_amdgcn_mfma_f32_16x16x16f16(lo4(WP2), h1, acc2[1][4], 0,0,0); \
    acc2[0][5] = __builtin_amdgcn_mfma_f32_16x16x16f16(hi4(WP2), h0, acc2[0][5], 0,0,0); \
    acc2[1][5] = __builtin_amdgcn_mfma_f32_16x16x16f16(hi4(WP2), h1, acc2[1][5], 0,0,0); \
  }

#define CLOADA(HT)                                                                    \
  a0A = W1f[(0 * NT1C + (HT)) * 64 + l];                                              \
  a1A = W1f[(1 * NT1C + (HT)) * 64 + l];                                              \
  a2A = W1f[(2 * NT1C + (HT)) * 64 + l];                                              \
  p0A = W2f[((HT) * 3 + 0) * 64 + l];                                                 \
  p1A = W2f[((HT) * 3 + 1) * 64 + l];                                                 \
  p2A = W2f[((HT) * 3 + 2) * 64 + l];                                                 \
  iA0 = *(const floatx4*)(bw0 + (HT) * 16 + q * 4);                                   \
  iA1 = *(const floatx4*)(bw1 + (HT) * 16 + q * 4);

#define CLOADB(HT)                                                                    \
  a0B = W1f[(0 * NT1C + (HT)) * 64 + l];                                              \
  a1B = W1f[(1 * NT1C + (HT)) * 64 + l];                                              \
  a2B = W1f[(2 * NT1C + (HT)) * 64 + l];                                              \
  p0B = W2f[((HT) * 3 + 0) * 64 + l];                                                 \
  p1B = W2f[((HT) * 3 + 1) * 64 + l];                                                 \
  p2B = W2f[((HT) * 3 + 2) * 64 + l];                                                 \
  iB0 = *(const floatx4*)(bw0 + (HT) * 16 + q * 4);                                   \
  iB1 = *(const floatx4*)(bw1 + (HT) * 16 + q * 4);

// Check-node MLP, 32 rows/wave (2 row-groups), register-direct, LUT-gelu,
// 2-deep prefetch rotation over the full load set.
__global__ __launch_bounds__(256, 3) void kernelC(
    const _Float16* __restrict__ Mc, const int* __restrict__ synd,
    _Float16* __restrict__ Yc,
    const _Float16* __restrict__ W1p, const _Float16* __restrict__ W2p,
    const float* __restrict__ bwp, const float* __restrict__ bwm,
    const float* __restrict__ b2)
{
  __shared__ float2 tab[1024];
  BUILD_TAB(tab)

  const int tid = threadIdx.x, w = tid >> 6, l = tid & 63;
  const int q = l >> 4, c = l & 15;
  const int r0 = blockIdx.x * 128 + w * 32;

  half8 mb[2][3];
  float sg[2];
  #pragma unroll
  for (int rg = 0; rg < 2; ++rg) {
    const _Float16* Arow = Mc + (size_t)(r0 + rg * 16 + c) * KC;
    #pragma unroll
    for (int ks = 0; ks < 3; ++ks)
      mb[rg][ks] = *(const half8*)(Arow + ks * 32 + q * 8);
    sg[rg] = 1.0f - 2.0f * (float)synd[r0 + rg * 16 + c];
  }
  const float* bw0 = (sg[0] > 0.0f) ? bwp : bwm;
  const float* bw1 = (sg[1] > 0.0f) ? bwp : bwm;

  floatx4 acc2[2][6];
  #pragma unroll
  for (int rg = 0; rg < 2; ++rg)
    #pragma unroll
    for (int nt = 0; nt < 6; ++nt)
      acc2[rg][nt] = (floatx4){0.f, 0.f, 0.f, 0.f};

  const half8* W1f = (const half8*)W1p;
  const half8* W2f = (const half8*)W2p;

  half8 a0A, a1A, a2A, p0A, p1A, p2A;
  half8 a0B, a1B, a2B, p0B, p1B, p2B;
  floatx4 iA0, iA1, iB0, iB1;
  CLOADA(0)

  #pragma unroll 1
  for (int i = 0; i < 13; ++i) {
    const int h1 = 2 * i + 1;
    CLOADB(h1)                       // issue next-tile loads first
    CSTEP(a0A, a1A, a2A, p0A, p1A, p2A, iA0, iA1)
    const int h2 = (2 * i + 2 < NT1C) ? 2 * i + 2 : NT1C - 1;  // last: harmless re-read
    CLOADA(h2)
    CSTEP(a0B, a1B, a2B, p0B, p1B, p2B, iB0, iB1)
  }

  #pragma unroll
  for (int rg = 0; rg < 2; ++rg) {
    const size_t row = (size_t)(r0 + rg * 16 + c);
    #pragma unroll
    for (int nt = 0; nt < 6; ++nt) {
      floatx4 bia = *(const floatx4*)(b2 + nt * 16 + q * 4);
      half4 yy;
      #pragma unroll
      for (int r = 0; r < 4; ++r)
        yy[r] = (_Float16)((acc2[rg][nt][r] + bia[r]) * sg[rg]);
      *(half4*)(Yc + row * 96 + nt * 16 + q * 4) = yy;
    }
  }
}

// one ht-step of the var MLP, two row-groups sharing one C-init vector
#define VSTEP(WA0, WA1, WP0, WP1, WI)                                                    \
  {                                                                                      \
    floatx4 a0 = WI, a1 = WI;                                                            \
    a0 = __builtin_amdgcn_mfma_f32_16x16x32_f16(WA0, mb[0][0], a0, 0, 0, 0);             \
    a1 = __builtin_amdgcn_mfma_f32_16x16x32_f16(WA0, mb[1][0], a1, 0, 0, 0);             \
    a0 = __builtin_amdgcn_mfma_f32_16x16x32_f16(WA1, mb[0][1], a0, 0, 0, 0);             \
    a1 = __builtin_amdgcn_mfma_f32_16x16x32_f16(WA1, mb[1][1], a1, 0, 0, 0);             \
    half4 h0, h1;                                                                        \
    _Pragma("unroll")                                                                    \
    for (int r = 0; r < 4; ++r) h0[r] = (_Float16)gelu_lut(tab, a0[r]);                  \
    _Pragma("unroll")                                                                    \
    for (int r = 0; r < 4; ++r) h1[r] = (_Float16)gelu_lut(tab, a1[r]);                  \
    acc2[0][0] = __builtin_amdgcn_mfma_f32_16x16x16f16(lo4(WP0), h0, acc2[0][0], 0,0,0); \
    acc2[1][0] = __builtin_amdgcn_mfma_f32_16x16x16f16(lo4(WP0), h1, acc2[1][0], 0,0,0); \
    acc2[0][1] = __builtin_amdgcn_mfma_f32_16x16x16f16(hi4(WP0), h0, acc2[0][1], 0,0,0); \
    acc2[1][1] = __builtin_amdgcn_mfma_f32_16x16x16f16(hi4(WP0), h1, acc2[1][1], 0,0,0); \
    acc2[0][2] = __builtin_amdgcn_mfma_f32_16x16x16f16(lo4(WP1), h0, acc2[0][2], 0,0,0); \
    acc2[1][2] = __builtin_amdgcn_mfma_f32_16x16x16f16(lo4(WP1), h1, acc2[1][2], 0,0,0); \
    acc2[0][3] = __builtin_amdgcn_mfma_f32_16x16x16f16(hi4(WP1), h0, acc2[0][3], 0,0,0); \
    acc2[1][3] = __builtin_amdgcn_mfma_f32_16x16x16f16(hi4(WP1), h1, acc2[1][3], 0,0,0); \
  }

#define VLOADA(HT)                                                                    \
  a0A = W1f[(0 * NT1V + (HT)) * 64 + l];                                              \
  a1A = W1f[(1 * NT1V + (HT)) * 64 + l];                                              \
  p0A = W2f[((HT) * 2 + 0) * 64 + l];                                                 \
  p1A = W2f[((HT) * 2 + 1) * 64 + l];                                                 \
  iA  = *(const floatx4*)(b1 + (HT) * 16 + q * 4);

#define VLOADB(HT)                                                                    \
  a0B = W1f[(0 * NT1V + (HT)) * 64 + l];                                              \
  a1B = W1f[(1 * NT1V + (HT)) * 64 + l];                                              \
  p0B = W2f[((HT) * 2 + 0) * 64 + l];                                                 \
  p1B = W2f[((HT) * 2 + 1) * 64 + l];                                                 \
  iB  = *(const floatx4*)(b1 + (HT) * 16 + q * 4);

// Variable-node MLP, 32 vars/wave (2 row-groups), LUT-gelu, full prefetch
// rotation (NT1V=13 odd: 6 pairs + tail).
__global__ __launch_bounds__(256, 4) void kernelV(
    const _Float16* __restrict__ Yc, const int* __restrict__ perm,
    const float* __restrict__ prior,
    _Float16* __restrict__ Mc, float* __restrict__ outp,
    const _Float16* __restrict__ W1p, const _Float16* __restrict__ W2p,
    const float* __restrict__ b1, const float* __restrict__ b2)
{
  __shared__ float2 tab[1024];
  BUILD_TAB(tab)

  const int tid = threadIdx.x, w = tid >> 6, l = tid & 63;
  const int q = l >> 4, c = l & 15;
  const int r0 = blockIdx.x * 128 + w * 32;   // 1024-aligned batch: 32 | 1024
  const int b  = r0 >> 10;
  const int v0 = r0 & 1023;
  const size_t yb = (size_t)b * EDGE;

  half8 mb[2][2];
  #pragma unroll
  for (int rg = 0; rg < 2; ++rg) {
    int v = v0 + rg * 16 + c;
    int e0 = perm[3 * v + (q >> 1)];
    mb[rg][0] = *(const half8*)(Yc + (yb + e0) * 16 + (q & 1) * 8);
    half8 m1 = {0,0,0,0,0,0,0,0};
    if (q < 2) {
      int e2 = perm[3 * v + 2];
      m1 = *(const half8*)(Yc + (yb + e2) * 16 + q * 8);
    } else if (q == 2) {
      m1[0] = (_Float16)prior[v];
    }
    mb[rg][1] = m1;
  }

  floatx4 acc2[2][4];
  #pragma unroll
  for (int rg = 0; rg < 2; ++rg)
    #pragma unroll
    for (int nt = 0; nt < 4; ++nt)
      acc2[rg][nt] = (floatx4){0.f, 0.f, 0.f, 0.f};

  const half8* W1f = (const half8*)W1p;
  const half8* W2f = (const half8*)W2p;

  half8 a0A, a1A, p0A, p1A;
  half8 a0B, a1B, p0B, p1B;
  floatx4 iA, iB;
  VLOADA(0)

  #pragma unroll 1
  for (int i = 0; i < 6; ++i) {
    const int h1 = 2 * i + 1;
    VLOADB(h1)
    VSTEP(a0A, a1A, p0A, p1A, iA)
    VLOADA(2 * i + 2)
    VSTEP(a0B, a1B, p0B, p1B, iB)
  }
  VSTEP(a0A, a1A, p0A, p1A, iA)      // ht = 12 (loaded by VLOADA at i=5)

  const float bllr = b2[48];
  #pragma unroll
  for (int rg = 0; rg < 2; ++rg) {
    int v = v0 + rg * 16 + c;
    #pragma unroll
    for (int nt = 0; nt < 3; ++nt) {
      int pe = perm[3 * v + nt];
      floatx4 bia = *(const floatx4*)(b2 + nt * 16 + q * 4);
      half4 yy;
      #pragma unroll
      for (int r = 0; r < 4; ++r)
        yy[r] = (_Float16)(acc2[rg][nt][r] + bia[r]);
      *(half4*)(Mc + (yb + pe) * 16 + q * 4) = yy;
    }
    if (q == 0)
      outp[r0 + rg * 16 + c] = acc2[rg][3][0] + bllr;
  }
}

extern "C" void kernel_launch(void* const* d_in, const int* in_sizes, int n_in,
                              void* d_out, int out_size, void* d_ws, size_t ws_size,
                              hipStream_t stream)
{
  const int*   synd  = (const int*)d_in[0];
  const float* prior = (const float*)d_in[2];
  const int*   perm  = (const int*)d_in[3];
  const float* cW1 = (const float*)d_in[4];
  const float* cb1 = (const float*)d_in[5];
  const float* cW2 = (const float*)d_in[6];
  const float* cb2 = (const float*)d_in[7];
  const float* vW1 = (const float*)d_in[8];
  const float* vb1 = (const float*)d_in[9];
  const float* vW2 = (const float*)d_in[10];
  const float* vb2 = (const float*)d_in[11];
  float* outp = (float*)d_out;
  const int T = out_size / (BATCH * NVAR);

  char* p = (char*)d_ws;
  _Float16* Mc  = (_Float16*)p; p += (size_t)BATCH * EDGE * 16 * 2;
  _Float16* Yc  = (_Float16*)p; p += (size_t)BATCH * EDGE * 16 * 2;
  _Float16* w1c = (_Float16*)p; p += (size_t)KS1C * NT1C * 64 * 8 * 2;
  _Float16* w2c = (_Float16*)p; p += (size_t)NT1C * 3 * 64 * 8 * 2;
  _Float16* w1v = (_Float16*)p; p += (size_t)KS1V * NT1V * 64 * 8 * 2;
  _Float16* w2v = (_Float16*)p; p += (size_t)NT1V * 2 * 64 * 8 * 2;
  float* bwp  = (float*)p; p += 416 * 4;
  float* bwm  = (float*)p; p += 416 * 4;
  float* b2c  = (float*)p; p += 96 * 4;
  float* b1v  = (float*)p; p += 208 * 4;
  float* b2v  = (float*)p; p += 64 * 4;

  const int packN = KS1C * NT1C * 64 + NT1C * 3 * 64 + KS1V * NT1V * 64 +
                    NT1V * 2 * 64 + 416 + 416 + 96 + 208 + 64;   // 14512
  pack_kernel<<<(packN + 255) / 256, 256, 0, stream>>>(
      cW1, cb1, cW2, cb2, vW1, vb1, vW2, vb2,
      w1c, w2c, w1v, w2v, bwp, bwm, b2c, b1v, b2v);
  init_kernel<<<(BATCH * EDGE) / 256, 256, 0, stream>>>(perm, prior, Mc);

  for (int t = 0; t < T; ++t) {
    kernelC<<<(BATCH * NCHK) / 128, 256, 0, stream>>>(
        Mc, synd, Yc, w1c, w2c, bwp, bwm, b2c);
    kernelV<<<(BATCH * NVAR) / 128, 256, 0, stream>>>(
        Yc, perm, prior, Mc, outp + (size_t)t * BATCH * NVAR, w1v, w2v, b1v, b2v);
  }
}

// Round 9
// 509.523 us; speedup vs baseline: 1.2769x; 1.2769x over previous
//
#include <hip/hip_runtime.h>
#include <cstdint>
#include <cstddef>

typedef _Float16 half8 __attribute__((ext_vector_type(8)));
typedef _Float16 half4 __attribute__((ext_vector_type(4)));
typedef float floatx4 __attribute__((ext_vector_type(4)));

#define BATCH 256
#define NCHK 512
#define NVAR 1024
#define EDGE 3072

// ---- check MLP tiling ----
#define KC    96
#define NT1C  26     // hidden 388 -> 416 -> 26 col-tiles of 16 (13 chunks of 2)
// ---- var MLP tiling ----
#define NT1VP 14     // hidden 196 -> 224 -> 14 col-tiles of 16 (7 chunks of 2; pad tile is exact-zero)

__device__ __forceinline__ float gelu_f(float x) {
  // exact gelu via A&S 7.1.26 erf approx, |err(erf)| < 1.5e-7 (table builder only)
  float ax = fabsf(x) * 0.70710678118654752440f;
  float t  = 1.0f / fmaf(0.3275911f, ax, 1.0f);
  float p  = t * (0.254829592f + t * (-0.284496736f + t * (1.421413741f +
             t * (-1.453152027f + t * 1.061405429f))));
  float e  = __expf(-ax * ax);
  float erfv = fmaf(-p, e, 1.0f);
  float s  = copysignf(erfv, x);
  float hx = 0.5f * x;
  return fmaf(hx, s, hx);
}

// PWL gelu: 1024 segments over [-8,8], node+slope in LDS (float2, ds_read_b64).
// |err| <= (1/64)^2/8 * 0.8 ~ 2.4e-5. Out of range: h += max(t-tc,0)/64.
__device__ __forceinline__ float gelu_lut(const float2* __restrict__ tab, float x) {
  float t  = fmaf(x, 64.0f, 512.0f);
  float tc = fminf(fmaxf(t, 0.0f), 1023.0f);
  float tf = __builtin_truncf(tc);
  float fr = tc - tf;
  int idx  = (int)tf;
  float2 ns = tab[idx];
  float h  = fmaf(fr, ns.y, ns.x);
  return fmaf(fmaxf(t - tc, 0.0f), 0.015625f, h);
}

__device__ __forceinline__ half4 lo4(half8 v) {
  return __builtin_shufflevector(v, v, 0, 1, 2, 3);
}
__device__ __forceinline__ half4 hi4(half8 v) {
  return __builtin_shufflevector(v, v, 4, 5, 6, 7);
}

// Weight packs, CHUNK-CONTIGUOUS for block-level LDS staging:
// w1c: frag (ht*3 + s): [(ht*3+s)*64 + l][j] = W1[k=s*32+(l>>4)*8+j][n=ht*16+(l&15)]
// w2c: frag (ht*3 + p) (K16 pairs): [..][j] = W2[k=ht*16+(l>>4)*4+(j&3)][n=(2p+(j>>2))*16+(l&15)]
// w1v/w2v: same with 2 frags per ht, NT1VP=14 tiles (pad tiles exact-zero).
// bwp/bwm = cb1 +/- cW1[96] (fp32 exact for sg=+/-1).
__global__ void pack_kernel(const float* __restrict__ cW1, const float* __restrict__ cb1,
                            const float* __restrict__ cW2, const float* __restrict__ cb2,
                            const float* __restrict__ vW1, const float* __restrict__ vb1,
                            const float* __restrict__ vW2, const float* __restrict__ vb2,
                            _Float16* __restrict__ w1c, _Float16* __restrict__ w2c,
                            _Float16* __restrict__ w1v, _Float16* __restrict__ w2v,
                            float* __restrict__ bwp, float* __restrict__ bwm,
                            float* __restrict__ b2c, float* __restrict__ b1v,
                            float* __restrict__ b2v)
{
  int id = blockIdx.x * 256 + threadIdx.x;
  const int S0 = NT1C * 3 * 64;    // 4992
  const int S1 = NT1C * 3 * 64;    // 4992
  const int S2 = NT1VP * 2 * 64;   // 1792
  const int S3 = NT1VP * 2 * 64;   // 1792
  if (id < S0) {
    int fh = id / 64, l = id % 64;
    int ht = fh / 3, s = fh % 3;
    int q = l >> 4, n = ht * 16 + (l & 15);
    half8 v;
    #pragma unroll
    for (int j = 0; j < 8; ++j) {
      int k = s * 32 + q * 8 + j;
      float x = (n < 388) ? cW1[k * 388 + n] : 0.0f;
      v[j] = (_Float16)x;
    }
    *(half8*)(w1c + (size_t)id * 8) = v;
    return;
  }
  id -= S0;
  if (id < S1) {
    int fh = id / 64, l = id % 64;
    int ht = fh / 3, np = fh % 3;
    int q = l >> 4, c = l & 15;
    half8 v;
    #pragma unroll
    for (int j = 0; j < 8; ++j) {
      int k = ht * 16 + q * 4 + (j & 3);
      int n = (2 * np + (j >> 2)) * 16 + c;
      float x = (k < 388) ? cW2[k * 96 + n] : 0.0f;
      v[j] = (_Float16)x;
    }
    *(half8*)(w2c + (size_t)id * 8) = v;
    return;
  }
  id -= S1;
  if (id < S2) {
    int fh = id / 64, l = id % 64;
    int ht = fh / 2, s = fh % 2;
    int q = l >> 4, n = ht * 16 + (l & 15);
    half8 v;
    #pragma unroll
    for (int j = 0; j < 8; ++j) {
      int k = s * 32 + q * 8 + j;                        // row 48 = prior row
      float x = (k < 49 && n < 196) ? vW1[k * 196 + n] : 0.0f;
      v[j] = (_Float16)x;
    }
    *(half8*)(w1v + (size_t)id * 8) = v;
    return;
  }
  id -= S2;
  if (id < S3) {
    int fh = id / 64, l = id % 64;
    int ht = fh / 2, np = fh % 2;
    int q = l >> 4, c = l & 15;
    half8 v;
    #pragma unroll
    for (int j = 0; j < 8; ++j) {
      int k = ht * 16 + q * 4 + (j & 3);
      int n = (2 * np + (j >> 2)) * 16 + c;
      float x = (k < 196 && n < 49) ? vW2[k * 49 + n] : 0.0f;
      v[j] = (_Float16)x;
    }
    *(half8*)(w2v + (size_t)id * 8) = v;
    return;
  }
  id -= S3;
  if (id < 416) {
    float b = (id < 388) ? cb1[id] : 0.0f;
    float wv = (id < 388) ? cW1[96 * 388 + id] : 0.0f;
    bwp[id] = b + wv;
    return;
  }
  id -= 416;
  if (id < 416) {
    float b = (id < 388) ? cb1[id] : 0.0f;
    float wv = (id < 388) ? cW1[96 * 388 + id] : 0.0f;
    bwm[id] = b - wv;
    return;
  }
  id -= 416;
  if (id < 96)  { b2c[id]  = cb2[id]; return; }
  id -= 96;
  if (id < 224) { b1v[id]  = (id < 196) ? vb1[id] : 0.0f; return; }
  id -= 224;
  if (id < 64)  { b2v[id]  = (id < 49) ? vb2[id] : 0.0f; return; }
}

__global__ void init_kernel(const int* __restrict__ perm, const float* __restrict__ prior,
                            _Float16* __restrict__ Mc)
{
  int t = blockIdx.x * 256 + threadIdx.x;   // t < BATCH*EDGE
  int b = t / EDGE, k = t - b * EDGE;
  int e = perm[k];
  _Float16* dst = Mc + ((size_t)b * EDGE + e) * 16;
  half8 z  = {0,0,0,0,0,0,0,0};
  half8 z0 = z;
  z0[0] = (_Float16)prior[k / 3];
  *(half8*)dst = z0;
  *(half8*)(dst + 8) = z;
}

// one ht-step of the check MLP, rg=2, ALL operands from LDS (weights staged
// per chunk by the block; bias tables resident). HTG = global hidden tile,
// HTS = tile within chunk (0/1).
#define CSTEPL(HTG, HTS)                                                                 \
  {                                                                                      \
    half8 wa0 = wb[((HTS) * 3 + 0) * 64 + l];                                            \
    half8 wa1 = wb[((HTS) * 3 + 1) * 64 + l];                                            \
    half8 wa2 = wb[((HTS) * 3 + 2) * 64 + l];                                            \
    half8 wp0 = wb[384 + ((HTS) * 3 + 0) * 64 + l];                                      \
    half8 wp1 = wb[384 + ((HTS) * 3 + 1) * 64 + l];                                      \
    half8 wp2 = wb[384 + ((HTS) * 3 + 2) * 64 + l];                                      \
    floatx4 a0 = *(const floatx4*)&bwL[sel0 + (HTG) * 16 + q * 4];                       \
    floatx4 a1 = *(const floatx4*)&bwL[sel1 + (HTG) * 16 + q * 4];                       \
    a0 = __builtin_amdgcn_mfma_f32_16x16x32_f16(wa0, mb[0][0], a0, 0, 0, 0);             \
    a1 = __builtin_amdgcn_mfma_f32_16x16x32_f16(wa0, mb[1][0], a1, 0, 0, 0);             \
    a0 = __builtin_amdgcn_mfma_f32_16x16x32_f16(wa1, mb[0][1], a0, 0, 0, 0);             \
    a1 = __builtin_amdgcn_mfma_f32_16x16x32_f16(wa1, mb[1][1], a1, 0, 0, 0);             \
    a0 = __builtin_amdgcn_mfma_f32_16x16x32_f16(wa2, mb[0][2], a0, 0, 0, 0);             \
    a1 = __builtin_amdgcn_mfma_f32_16x16x32_f16(wa2, mb[1][2], a1, 0, 0, 0);             \
    half4 h0, h1;                                                                        \
    _Pragma("unroll")                                                                    \
    for (int r = 0; r < 4; ++r) h0[r] = (_Float16)gelu_lut(tab, a0[r]);                  \
    _Pragma("unroll")                                                                    \
    for (int r = 0; r < 4; ++r) h1[r] = (_Float16)gelu_lut(tab, a1[r]);                  \
    acc2[0][0] = __builtin_amdgcn_mfma_f32_16x16x16f16(lo4(wp0), h0, acc2[0][0], 0,0,0); \
    acc2[1][0] = __builtin_amdgcn_mfma_f32_16x16x16f16(lo4(wp0), h1, acc2[1][0], 0,0,0); \
    acc2[0][1] = __builtin_amdgcn_mfma_f32_16x16x16f16(hi4(wp0), h0, acc2[0][1], 0,0,0); \
    acc2[1][1] = __builtin_amdgcn_mfma_f32_16x16x16f16(hi4(wp0), h1, acc2[1][1], 0,0,0); \
    acc2[0][2] = __builtin_amdgcn_mfma_f32_16x16x16f16(lo4(wp1), h0, acc2[0][2], 0,0,0); \
    acc2[1][2] = __builtin_amdgcn_mfma_f32_16x16x16f16(lo4(wp1), h1, acc2[1][2], 0,0,0); \
    acc2[0][3] = __builtin_amdgcn_mfma_f32_16x16x16f16(hi4(wp1), h0, acc2[0][3], 0,0,0); \
    acc2[1][3] = __builtin_amdgcn_mfma_f32_16x16x16f16(hi4(wp1), h1, acc2[1][3], 0,0,0); \
    acc2[0][4] = __builtin_amdgcn_mfma_f32_16x16x16f16(lo4(wp2), h0, acc2[0][4], 0,0,0); \
    acc2[1][4] = __builtin_amdgcn_mfma_f32_16x16x16f16(lo4(wp2), h1, acc2[1][4], 0,0,0); \
    acc2[0][5] = __builtin_amdgcn_mfma_f32_16x16x16f16(hi4(wp2), h0, acc2[0][5], 0,0,0); \
    acc2[1][5] = __builtin_amdgcn_mfma_f32_16x16x16f16(hi4(wp2), h1, acc2[1][5], 0,0,0); \
  }

// Check-node MLP, 32 rows/wave, 128 rows/block. Weight chunks (2 ht = 12 KB)
// staged through double-buffered LDS by the whole block: global weight
// traffic /4 vs per-wave loads (R7-R8 limiter: redundant L1/L2 weight
// refetch). Main loop has NO VMEM except the 6 staging loads per chunk.
// One __syncthreads per chunk; grid 1024 = 4 blocks/CU, single tranche.
__global__ __launch_bounds__(256, 4) void kernelC(
    const _Float16* __restrict__ Mc, const int* __restrict__ synd,
    _Float16* __restrict__ Yc,
    const _Float16* __restrict__ W1p, const _Float16* __restrict__ W2p,
    const float* __restrict__ bwp, const float* __restrict__ bwm,
    const float* __restrict__ b2)
{
  __shared__ float2 tab[1024];                               // 8 KB
  __shared__ __attribute__((aligned(16))) float bwL[832];    // 3.3 KB: [bwp | bwm]
  __shared__ half8 wbuf[2][768];                             // 2 x 12 KB chunks

  const int tid = threadIdx.x, w = tid >> 6, l = tid & 63;
  const int q = l >> 4, c = l & 15;
  const int r0 = blockIdx.x * 128 + w * 32;

  // ---- prologue fills (one barrier covers all) ----
  for (int k_ = tid; k_ < 1024; k_ += 256) {
    float x_  = (k_ - 512) * 0.015625f;
    float y0_ = gelu_f(x_);
    float y1_ = gelu_f(x_ + 0.015625f);
    tab[k_] = make_float2(y0_, y1_ - y0_);
  }
  for (int k_ = tid; k_ < 416; k_ += 256) {
    bwL[k_]       = bwp[k_];
    bwL[416 + k_] = bwm[k_];
  }
  {
    const half8* g1 = (const half8*)W1p;   // chunk 0: entries 0..383
    const half8* g2 = (const half8*)W2p;
    wbuf[0][tid]       = g1[tid];
    wbuf[0][256 + tid] = (tid < 128) ? g1[256 + tid] : g2[tid - 128];
    wbuf[0][512 + tid] = g2[128 + tid];
  }

  // Mc fragments (B-operand: lane holds batch-row n = l&15, k = q*8+j)
  half8 mb[2][3];
  float sg[2];
  #pragma unroll
  for (int rg = 0; rg < 2; ++rg) {
    const _Float16* Arow = Mc + (size_t)(r0 + rg * 16 + c) * KC;
    #pragma unroll
    for (int ks = 0; ks < 3; ++ks)
      mb[rg][ks] = *(const half8*)(Arow + ks * 32 + q * 8);
    sg[rg] = 1.0f - 2.0f * (float)synd[r0 + rg * 16 + c];
  }
  const int sel0 = (sg[0] > 0.0f) ? 0 : 416;
  const int sel1 = (sg[1] > 0.0f) ? 0 : 416;

  floatx4 acc2[2][6];
  #pragma unroll
  for (int rg = 0; rg < 2; ++rg)
    #pragma unroll
    for (int nt = 0; nt < 6; ++nt)
      acc2[rg][nt] = (floatx4){0.f, 0.f, 0.f, 0.f};

  __syncthreads();

  int cur = 0;
  #pragma unroll 1
  for (int i = 0; i < 13; ++i) {
    half8 st0, st1, st2;
    if (i < 12) {                       // issue next-chunk loads early
      const half8* g1 = (const half8*)W1p + (i + 1) * 384;
      const half8* g2 = (const half8*)W2p + (i + 1) * 384;
      st0 = g1[tid];
      st1 = (tid < 128) ? g1[256 + tid] : g2[tid - 128];
      st2 = g2[128 + tid];
    }
    const half8* wb = (const half8*)wbuf[cur];
    CSTEPL(2 * i,     0)
    CSTEPL(2 * i + 1, 1)
    if (i < 12) {                       // land next chunk, one barrier/chunk
      half8* wbn = (half8*)wbuf[cur ^ 1];
      wbn[tid]       = st0;
      wbn[256 + tid] = st1;
      wbn[512 + tid] = st2;
      __syncthreads();
      cur ^= 1;
    }
  }

  #pragma unroll
  for (int rg = 0; rg < 2; ++rg) {
    const size_t row = (size_t)(r0 + rg * 16 + c);
    #pragma unroll
    for (int nt = 0; nt < 6; ++nt) {
      floatx4 bia = *(const floatx4*)(b2 + nt * 16 + q * 4);
      half4 yy;
      #pragma unroll
      for (int r = 0; r < 4; ++r)
        yy[r] = (_Float16)((acc2[rg][nt][r] + bia[r]) * sg[rg]);
      *(half4*)(Yc + row * 96 + nt * 16 + q * 4) = yy;
    }
  }
}

// one ht-step of the var MLP, rg=2, operands from LDS
#define VSTEPL(HTG, HTS)                                                                 \
  {                                                                                      \
    half8 wa0 = wb[((HTS) * 2 + 0) * 64 + l];                                            \
    half8 wa1 = wb[((HTS) * 2 + 1) * 64 + l];                                            \
    half8 wp0 = wb[256 + ((HTS) * 2 + 0) * 64 + l];                                      \
    half8 wp1 = wb[256 + ((HTS) * 2 + 1) * 64 + l];                                      \
    floatx4 i0 = *(const floatx4*)&b1L[(HTG) * 16 + q * 4];                              \
    floatx4 a0 = i0, a1 = i0;                                                            \
    a0 = __builtin_amdgcn_mfma_f32_16x16x32_f16(wa0, mb[0][0], a0, 0, 0, 0);             \
    a1 = __builtin_amdgcn_mfma_f32_16x16x32_f16(wa0, mb[1][0], a1, 0, 0, 0);             \
    a0 = __builtin_amdgcn_mfma_f32_16x16x32_f16(wa1, mb[0][1], a0, 0, 0, 0);             \
    a1 = __builtin_amdgcn_mfma_f32_16x16x32_f16(wa1, mb[1][1], a1, 0, 0, 0);             \
    half4 h0, h1;                                                                        \
    _Pragma("unroll")                                                                    \
    for (int r = 0; r < 4; ++r) h0[r] = (_Float16)gelu_lut(tab, a0[r]);                  \
    _Pragma("unroll")                                                                    \
    for (int r = 0; r < 4; ++r) h1[r] = (_Float16)gelu_lut(tab, a1[r]);                  \
    acc2[0][0] = __builtin_amdgcn_mfma_f32_16x16x16f16(lo4(wp0), h0, acc2[0][0], 0,0,0); \
    acc2[1][0] = __builtin_amdgcn_mfma_f32_16x16x16f16(lo4(wp0), h1, acc2[1][0], 0,0,0); \
    acc2[0][1] = __builtin_amdgcn_mfma_f32_16x16x16f16(hi4(wp0), h0, acc2[0][1], 0,0,0); \
    acc2[1][1] = __builtin_amdgcn_mfma_f32_16x16x16f16(hi4(wp0), h1, acc2[1][1], 0,0,0); \
    acc2[0][2] = __builtin_amdgcn_mfma_f32_16x16x16f16(lo4(wp1), h0, acc2[0][2], 0,0,0); \
    acc2[1][2] = __builtin_amdgcn_mfma_f32_16x16x16f16(lo4(wp1), h1, acc2[1][2], 0,0,0); \
    acc2[0][3] = __builtin_amdgcn_mfma_f32_16x16x16f16(hi4(wp1), h0, acc2[0][3], 0,0,0); \
    acc2[1][3] = __builtin_amdgcn_mfma_f32_16x16x16f16(hi4(wp1), h1, acc2[1][3], 0,0,0); \
  }

// Variable-node MLP, 32 vars/wave, 128 vars/block, same LDS chunk staging
// (7 chunks of 2 ht; tile 13 is exact-zero padding).
__global__ __launch_bounds__(256, 4) void kernelV(
    const _Float16* __restrict__ Yc, const int* __restrict__ perm,
    const float* __restrict__ prior,
    _Float16* __restrict__ Mc, float* __restrict__ outp,
    const _Float16* __restrict__ W1p, const _Float16* __restrict__ W2p,
    const float* __restrict__ b1, const float* __restrict__ b2)
{
  __shared__ float2 tab[1024];                               // 8 KB
  __shared__ __attribute__((aligned(16))) float b1L[224];    // 0.9 KB
  __shared__ half8 wbuf[2][512];                             // 2 x 8 KB chunks

  const int tid = threadIdx.x, w = tid >> 6, l = tid & 63;
  const int q = l >> 4, c = l & 15;
  const int r0 = blockIdx.x * 128 + w * 32;
  const int b  = r0 >> 10;
  const int v0 = r0 & 1023;
  const size_t yb = (size_t)b * EDGE;

  for (int k_ = tid; k_ < 1024; k_ += 256) {
    float x_  = (k_ - 512) * 0.015625f;
    float y0_ = gelu_f(x_);
    float y1_ = gelu_f(x_ + 0.015625f);
    tab[k_] = make_float2(y0_, y1_ - y0_);
  }
  if (tid < 224) b1L[tid] = b1[tid];
  {
    const half8* g1 = (const half8*)W1p;   // chunk 0: entries 0..255
    const half8* g2 = (const half8*)W2p;
    wbuf[0][tid]       = g1[tid];
    wbuf[0][256 + tid] = g2[tid];
  }

  // Xv^T fragments: lane holds var-row n = l&15, k = q*8+j
  half8 mb[2][2];
  #pragma unroll
  for (int rg = 0; rg < 2; ++rg) {
    int v = v0 + rg * 16 + c;
    int e0 = perm[3 * v + (q >> 1)];
    mb[rg][0] = *(const half8*)(Yc + (yb + e0) * 16 + (q & 1) * 8);
    half8 m1 = {0,0,0,0,0,0,0,0};
    if (q < 2) {
      int e2 = perm[3 * v + 2];
      m1 = *(const half8*)(Yc + (yb + e2) * 16 + q * 8);
    } else if (q == 2) {
      m1[0] = (_Float16)prior[v];
    }
    mb[rg][1] = m1;
  }

  floatx4 acc2[2][4];
  #pragma unroll
  for (int rg = 0; rg < 2; ++rg)
    #pragma unroll
    for (int nt = 0; nt < 4; ++nt)
      acc2[rg][nt] = (floatx4){0.f, 0.f, 0.f, 0.f};

  __syncthreads();

  int cur = 0;
  #pragma unroll 1
  for (int i = 0; i < 7; ++i) {
    half8 st0, st1;
    if (i < 6) {
      const half8* g1 = (const half8*)W1p + (i + 1) * 256;
      const half8* g2 = (const half8*)W2p + (i + 1) * 256;
      st0 = g1[tid];
      st1 = g2[tid];
    }
    const half8* wb = (const half8*)wbuf[cur];
    VSTEPL(2 * i,     0)
    VSTEPL(2 * i + 1, 1)
    if (i < 6) {
      half8* wbn = (half8*)wbuf[cur ^ 1];
      wbn[tid]       = st0;
      wbn[256 + tid] = st1;
      __syncthreads();
      cur ^= 1;
    }
  }

  const float bllr = b2[48];
  #pragma unroll
  for (int rg = 0; rg < 2; ++rg) {
    int v = v0 + rg * 16 + c;
    #pragma unroll
    for (int nt = 0; nt < 3; ++nt) {
      int pe = perm[3 * v + nt];
      floatx4 bia = *(const floatx4*)(b2 + nt * 16 + q * 4);
      half4 yy;
      #pragma unroll
      for (int r = 0; r < 4; ++r)
        yy[r] = (_Float16)(acc2[rg][nt][r] + bia[r]);
      *(half4*)(Mc + (yb + pe) * 16 + q * 4) = yy;
    }
    if (q == 0)
      outp[r0 + rg * 16 + c] = acc2[rg][3][0] + bllr;
  }
}

extern "C" void kernel_launch(void* const* d_in, const int* in_sizes, int n_in,
                              void* d_out, int out_size, void* d_ws, size_t ws_size,
                              hipStream_t stream)
{
  const int*   synd  = (const int*)d_in[0];
  const float* prior = (const float*)d_in[2];
  const int*   perm  = (const int*)d_in[3];
  const float* cW1 = (const float*)d_in[4];
  const float* cb1 = (const float*)d_in[5];
  const float* cW2 = (const float*)d_in[6];
  const float* cb2 = (const float*)d_in[7];
  const float* vW1 = (const float*)d_in[8];
  const float* vb1 = (const float*)d_in[9];
  const float* vW2 = (const float*)d_in[10];
  const float* vb2 = (const float*)d_in[11];
  float* outp = (float*)d_out;
  const int T = out_size / (BATCH * NVAR);

  char* p = (char*)d_ws;
  _Float16* Mc  = (_Float16*)p; p += (size_t)BATCH * EDGE * 16 * 2;
  _Float16* Yc  = (_Float16*)p; p += (size_t)BATCH * EDGE * 16 * 2;
  _Float16* w1c = (_Float16*)p; p += (size_t)NT1C * 3 * 64 * 8 * 2;
  _Float16* w2c = (_Float16*)p; p += (size_t)NT1C * 3 * 64 * 8 * 2;
  _Float16* w1v = (_Float16*)p; p += (size_t)NT1VP * 2 * 64 * 8 * 2;
  _Float16* w2v = (_Float16*)p; p += (size_t)NT1VP * 2 * 64 * 8 * 2;
  float* bwp  = (float*)p; p += 416 * 4;
  float* bwm  = (float*)p; p += 416 * 4;
  float* b2c  = (float*)p; p += 96 * 4;
  float* b1v  = (float*)p; p += 224 * 4;
  float* b2v  = (float*)p; p += 64 * 4;

  const int packN = NT1C * 3 * 64 * 2 + NT1VP * 2 * 64 * 2 +
                    416 + 416 + 96 + 224 + 64;   // 14784
  pack_kernel<<<(packN + 255) / 256, 256, 0, stream>>>(
      cW1, cb1, cW2, cb2, vW1, vb1, vW2, vb2,
      w1c, w2c, w1v, w2v, bwp, bwm, b2c, b1v, b2v);
  init_kernel<<<(BATCH * EDGE) / 256, 256, 0, stream>>>(perm, prior, Mc);

  for (int t = 0; t < T; ++t) {
    kernelC<<<(BATCH * NCHK) / 128, 256, 0, stream>>>(
        Mc, synd, Yc, w1c, w2c, bwp, bwm, b2c);
    kernelV<<<(BATCH * NVAR) / 128, 256, 0, stream>>>(
        Yc, perm, prior, Mc, outp + (size_t)t * BATCH * NVAR, w1v, w2v, b1v, b2v);
  }
}

// Round 10
// 488.578 us; speedup vs baseline: 1.3316x; 1.0429x over previous
//
#include <hip/hip_runtime.h>
#include <cstdint>
#include <cstddef>

typedef _Float16 half8 __attribute__((ext_vector_type(8)));
typedef _Float16 half4 __attribute__((ext_vector_type(4)));
typedef float floatx4 __attribute__((ext_vector_type(4)));

#define BATCH 256
#define NCHK 512
#define NVAR 1024
#define EDGE 3072

// ---- check MLP tiling ----
#define KC    96
#define NT1C  26     // hidden 388 -> 416 -> 26 col-tiles of 16 (13 chunks of 2)
// ---- var MLP tiling ----
#define NT1VP 14     // hidden 196 -> 224 -> 14 col-tiles of 16 (7 chunks of 2; pad tiles exact-zero)

__device__ __forceinline__ float gelu_f(float x) {
  // exact gelu via A&S 7.1.26 erf approx, |err(erf)| < 1.5e-7 (table builder only)
  float ax = fabsf(x) * 0.70710678118654752440f;
  float t  = 1.0f / fmaf(0.3275911f, ax, 1.0f);
  float p  = t * (0.254829592f + t * (-0.284496736f + t * (1.421413741f +
             t * (-1.453152027f + t * 1.061405429f))));
  float e  = __expf(-ax * ax);
  float erfv = fmaf(-p, e, 1.0f);
  float s  = copysignf(erfv, x);
  float hx = 0.5f * x;
  return fmaf(hx, s, hx);
}

// PWL gelu: 1024 segments over [-8,8], node+slope in LDS (float2, ds_read_b64).
// |err| <= (1/64)^2/8 * 0.8 ~ 2.4e-5. Out of range: h += max(t-tc,0)/64.
__device__ __forceinline__ float gelu_lut(const float2* __restrict__ tab, float x) {
  float t  = fmaf(x, 64.0f, 512.0f);
  float tc = fminf(fmaxf(t, 0.0f), 1023.0f);
  float tf = __builtin_truncf(tc);
  float fr = tc - tf;
  int idx  = (int)tf;
  float2 ns = tab[idx];
  float h  = fmaf(fr, ns.y, ns.x);
  return fmaf(fmaxf(t - tc, 0.0f), 0.015625f, h);
}

__device__ __forceinline__ half4 lo4(half8 v) {
  return __builtin_shufflevector(v, v, 0, 1, 2, 3);
}
__device__ __forceinline__ half4 hi4(half8 v) {
  return __builtin_shufflevector(v, v, 4, 5, 6, 7);
}

// Direct global->LDS DMA, 16B per lane. Dest is wave-uniform base + lane*16
// (HW rule, m104); source is per-lane. Removes the VGPR round-trip and the
// pre-barrier ds_write tail of R9's staging.
__device__ __forceinline__ void gload_lds16(const void* g, void* lds) {
  __builtin_amdgcn_global_load_lds(
      (const __attribute__((address_space(1))) unsigned int*)g,
      (__attribute__((address_space(3))) unsigned int*)lds, 16, 0, 0);
}

// Weight packs, CHUNK-CONTIGUOUS for block-level LDS staging:
// w1c: frag (ht*3 + s): [(ht*3+s)*64 + l][j] = W1[k=s*32+(l>>4)*8+j][n=ht*16+(l&15)]
// w2c: frag (ht*3 + p) (K16 pairs): [..][j] = W2[k=ht*16+(l>>4)*4+(j&3)][n=(2p+(j>>2))*16+(l&15)]
// w1v/w2v: same with 2 frags per ht, NT1VP=14 tiles (pad tiles exact-zero).
// bwp/bwm = cb1 +/- cW1[96] (fp32 exact for sg=+/-1).
__global__ void pack_kernel(const float* __restrict__ cW1, const float* __restrict__ cb1,
                            const float* __restrict__ cW2, const float* __restrict__ cb2,
                            const float* __restrict__ vW1, const float* __restrict__ vb1,
                            const float* __restrict__ vW2, const float* __restrict__ vb2,
                            _Float16* __restrict__ w1c, _Float16* __restrict__ w2c,
                            _Float16* __restrict__ w1v, _Float16* __restrict__ w2v,
                            float* __restrict__ bwp, float* __restrict__ bwm,
                            float* __restrict__ b2c, float* __restrict__ b1v,
                            float* __restrict__ b2v)
{
  int id = blockIdx.x * 256 + threadIdx.x;
  const int S0 = NT1C * 3 * 64;    // 4992
  const int S1 = NT1C * 3 * 64;    // 4992
  const int S2 = NT1VP * 2 * 64;   // 1792
  const int S3 = NT1VP * 2 * 64;   // 1792
  if (id < S0) {
    int fh = id / 64, l = id % 64;
    int ht = fh / 3, s = fh % 3;
    int q = l >> 4, n = ht * 16 + (l & 15);
    half8 v;
    #pragma unroll
    for (int j = 0; j < 8; ++j) {
      int k = s * 32 + q * 8 + j;
      float x = (n < 388) ? cW1[k * 388 + n] : 0.0f;
      v[j] = (_Float16)x;
    }
    *(half8*)(w1c + (size_t)id * 8) = v;
    return;
  }
  id -= S0;
  if (id < S1) {
    int fh = id / 64, l = id % 64;
    int ht = fh / 3, np = fh % 3;
    int q = l >> 4, c = l & 15;
    half8 v;
    #pragma unroll
    for (int j = 0; j < 8; ++j) {
      int k = ht * 16 + q * 4 + (j & 3);
      int n = (2 * np + (j >> 2)) * 16 + c;
      float x = (k < 388) ? cW2[k * 96 + n] : 0.0f;
      v[j] = (_Float16)x;
    }
    *(half8*)(w2c + (size_t)id * 8) = v;
    return;
  }
  id -= S1;
  if (id < S2) {
    int fh = id / 64, l = id % 64;
    int ht = fh / 2, s = fh % 2;
    int q = l >> 4, n = ht * 16 + (l & 15);
    half8 v;
    #pragma unroll
    for (int j = 0; j < 8; ++j) {
      int k = s * 32 + q * 8 + j;                        // row 48 = prior row
      float x = (k < 49 && n < 196) ? vW1[k * 196 + n] : 0.0f;
      v[j] = (_Float16)x;
    }
    *(half8*)(w1v + (size_t)id * 8) = v;
    return;
  }
  id -= S2;
  if (id < S3) {
    int fh = id / 64, l = id % 64;
    int ht = fh / 2, np = fh % 2;
    int q = l >> 4, c = l & 15;
    half8 v;
    #pragma unroll
    for (int j = 0; j < 8; ++j) {
      int k = ht * 16 + q * 4 + (j & 3);
      int n = (2 * np + (j >> 2)) * 16 + c;
      float x = (k < 196 && n < 49) ? vW2[k * 49 + n] : 0.0f;
      v[j] = (_Float16)x;
    }
    *(half8*)(w2v + (size_t)id * 8) = v;
    return;
  }
  id -= S3;
  if (id < 416) {
    float b = (id < 388) ? cb1[id] : 0.0f;
    float wv = (id < 388) ? cW1[96 * 388 + id] : 0.0f;
    bwp[id] = b + wv;
    return;
  }
  id -= 416;
  if (id < 416) {
    float b = (id < 388) ? cb1[id] : 0.0f;
    float wv = (id < 388) ? cW1[96 * 388 + id] : 0.0f;
    bwm[id] = b - wv;
    return;
  }
  id -= 416;
  if (id < 96)  { b2c[id]  = cb2[id]; return; }
  id -= 96;
  if (id < 224) { b1v[id]  = (id < 196) ? vb1[id] : 0.0f; return; }
  id -= 224;
  if (id < 64)  { b2v[id]  = (id < 49) ? vb2[id] : 0.0f; return; }
}

__global__ void init_kernel(const int* __restrict__ perm, const float* __restrict__ prior,
                            _Float16* __restrict__ Mc)
{
  int t = blockIdx.x * 256 + threadIdx.x;   // t < BATCH*EDGE
  int b = t / EDGE, k = t - b * EDGE;
  int e = perm[k];
  _Float16* dst = Mc + ((size_t)b * EDGE + e) * 16;
  half8 z  = {0,0,0,0,0,0,0,0};
  half8 z0 = z;
  z0[0] = (_Float16)prior[k / 3];
  *(half8*)dst = z0;
  *(half8*)(dst + 8) = z;
}

// one ht-step of the check MLP, rg=2, ALL operands from LDS.
#define CSTEPL(HTG, HTS)                                                                 \
  {                                                                                      \
    half8 wa0 = wb[((HTS) * 3 + 0) * 64 + l];                                            \
    half8 wa1 = wb[((HTS) * 3 + 1) * 64 + l];                                            \
    half8 wa2 = wb[((HTS) * 3 + 2) * 64 + l];                                            \
    half8 wp0 = wb[384 + ((HTS) * 3 + 0) * 64 + l];                                      \
    half8 wp1 = wb[384 + ((HTS) * 3 + 1) * 64 + l];                                      \
    half8 wp2 = wb[384 + ((HTS) * 3 + 2) * 64 + l];                                      \
    floatx4 a0 = *(const floatx4*)&bwL[sel0 + (HTG) * 16 + q * 4];                       \
    floatx4 a1 = *(const floatx4*)&bwL[sel1 + (HTG) * 16 + q * 4];                       \
    a0 = __builtin_amdgcn_mfma_f32_16x16x32_f16(wa0, mb[0][0], a0, 0, 0, 0);             \
    a1 = __builtin_amdgcn_mfma_f32_16x16x32_f16(wa0, mb[1][0], a1, 0, 0, 0);             \
    a0 = __builtin_amdgcn_mfma_f32_16x16x32_f16(wa1, mb[0][1], a0, 0, 0, 0);             \
    a1 = __builtin_amdgcn_mfma_f32_16x16x32_f16(wa1, mb[1][1], a1, 0, 0, 0);             \
    a0 = __builtin_amdgcn_mfma_f32_16x16x32_f16(wa2, mb[0][2], a0, 0, 0, 0);             \
    a1 = __builtin_amdgcn_mfma_f32_16x16x32_f16(wa2, mb[1][2], a1, 0, 0, 0);             \
    half4 h0, h1;                                                                        \
    _Pragma("unroll")                                                                    \
    for (int r = 0; r < 4; ++r) h0[r] = (_Float16)gelu_lut(tab, a0[r]);                  \
    _Pragma("unroll")                                                                    \
    for (int r = 0; r < 4; ++r) h1[r] = (_Float16)gelu_lut(tab, a1[r]);                  \
    acc2[0][0] = __builtin_amdgcn_mfma_f32_16x16x16f16(lo4(wp0), h0, acc2[0][0], 0,0,0); \
    acc2[1][0] = __builtin_amdgcn_mfma_f32_16x16x16f16(lo4(wp0), h1, acc2[1][0], 0,0,0); \
    acc2[0][1] = __builtin_amdgcn_mfma_f32_16x16x16f16(hi4(wp0), h0, acc2[0][1], 0,0,0); \
    acc2[1][1] = __builtin_amdgcn_mfma_f32_16x16x16f16(hi4(wp0), h1, acc2[1][1], 0,0,0); \
    acc2[0][2] = __builtin_amdgcn_mfma_f32_16x16x16f16(lo4(wp1), h0, acc2[0][2], 0,0,0); \
    acc2[1][2] = __builtin_amdgcn_mfma_f32_16x16x16f16(lo4(wp1), h1, acc2[1][2], 0,0,0); \
    acc2[0][3] = __builtin_amdgcn_mfma_f32_16x16x16f16(hi4(wp1), h0, acc2[0][3], 0,0,0); \
    acc2[1][3] = __builtin_amdgcn_mfma_f32_16x16x16f16(hi4(wp1), h1, acc2[1][3], 0,0,0); \
    acc2[0][4] = __builtin_amdgcn_mfma_f32_16x16x16f16(lo4(wp2), h0, acc2[0][4], 0,0,0); \
    acc2[1][4] = __builtin_amdgcn_mfma_f32_16x16x16f16(lo4(wp2), h1, acc2[1][4], 0,0,0); \
    acc2[0][5] = __builtin_amdgcn_mfma_f32_16x16x16f16(hi4(wp2), h0, acc2[0][5], 0,0,0); \
    acc2[1][5] = __builtin_amdgcn_mfma_f32_16x16x16f16(hi4(wp2), h1, acc2[1][5], 0,0,0); \
  }

// wave w DMA-stages its 3 of 12 segments of chunk CH into wbuf[BUF].
// Chunk = 384 entries of w1c (6 segs) + 384 of w2c (6 segs), 6144 B each.
#define CSTAGE(CH, BUF)                                                      \
  {                                                                          \
    if (w < 2) {                                                             \
      const char* gsrc = (const char*)W1p + (size_t)(CH) * 6144;             \
      _Pragma("unroll")                                                      \
      for (int s_ = 0; s_ < 3; ++s_)                                         \
        gload_lds16(gsrc + (((w * 3 + s_) * 64 + l) << 4),                   \
                    &wbuf[BUF][(w * 3 + s_) * 64]);                          \
    } else {                                                                 \
      const char* gsrc = (const char*)W2p + (size_t)(CH) * 6144;             \
      _Pragma("unroll")                                                      \
      for (int s_ = 0; s_ < 3; ++s_)                                         \
        gload_lds16(gsrc + ((((w - 2) * 3 + s_) * 64 + l) << 4),             \
                    &wbuf[BUF][(6 + (w - 2) * 3 + s_) * 64]);                \
    }                                                                        \
  }

// Check-node MLP, 32 rows/wave, 128 rows/block. Weight chunks (2 ht = 12 KB)
// staged via global_load_lds DMA (no VGPR round-trip, no ds_write tail) into
// double-buffered LDS; issued before the compute phase that hides their
// latency. One __syncthreads per chunk. Grid 1024 = 4 blocks/CU.
__global__ __launch_bounds__(256, 4) void kernelC(
    const _Float16* __restrict__ Mc, const int* __restrict__ synd,
    _Float16* __restrict__ Yc,
    const _Float16* __restrict__ W1p, const _Float16* __restrict__ W2p,
    const float* __restrict__ bwp, const float* __restrict__ bwm,
    const float* __restrict__ b2)
{
  __shared__ float2 tab[1024];                               // 8 KB
  __shared__ __attribute__((aligned(16))) float bwL[832];    // 3.3 KB: [bwp | bwm]
  __shared__ half8 wbuf[2][768];                             // 2 x 12 KB chunks

  const int tid = threadIdx.x, w = tid >> 6, l = tid & 63;
  const int q = l >> 4, c = l & 15;
  const int r0 = blockIdx.x * 128 + w * 32;

  CSTAGE(0, 0)                        // DMA chunk 0 under the prologue fills

  // ---- prologue fills (one barrier covers all, incl. DMA vmcnt) ----
  for (int k_ = tid; k_ < 1024; k_ += 256) {
    float x_  = (k_ - 512) * 0.015625f;
    float y0_ = gelu_f(x_);
    float y1_ = gelu_f(x_ + 0.015625f);
    tab[k_] = make_float2(y0_, y1_ - y0_);
  }
  for (int k_ = tid; k_ < 416; k_ += 256) {
    bwL[k_]       = bwp[k_];
    bwL[416 + k_] = bwm[k_];
  }

  // Mc fragments (B-operand: lane holds batch-row n = l&15, k = q*8+j)
  half8 mb[2][3];
  float sg[2];
  #pragma unroll
  for (int rg = 0; rg < 2; ++rg) {
    const _Float16* Arow = Mc + (size_t)(r0 + rg * 16 + c) * KC;
    #pragma unroll
    for (int ks = 0; ks < 3; ++ks)
      mb[rg][ks] = *(const half8*)(Arow + ks * 32 + q * 8);
    sg[rg] = 1.0f - 2.0f * (float)synd[r0 + rg * 16 + c];
  }
  const int sel0 = (sg[0] > 0.0f) ? 0 : 416;
  const int sel1 = (sg[1] > 0.0f) ? 0 : 416;

  floatx4 acc2[2][6];
  #pragma unroll
  for (int rg = 0; rg < 2; ++rg)
    #pragma unroll
    for (int nt = 0; nt < 6; ++nt)
      acc2[rg][nt] = (floatx4){0.f, 0.f, 0.f, 0.f};

  __syncthreads();

  int cur = 0;
  #pragma unroll 1
  for (int i = 0; i < 13; ++i) {
    if (i < 12) CSTAGE(i + 1, cur ^ 1)     // issue next-chunk DMA first
    const half8* wb = (const half8*)wbuf[cur];
    CSTEPL(2 * i,     0)
    CSTEPL(2 * i + 1, 1)
    if (i < 12) {
      __syncthreads();                     // drains DMA + publishes next chunk
      cur ^= 1;
    }
  }

  #pragma unroll
  for (int rg = 0; rg < 2; ++rg) {
    const size_t row = (size_t)(r0 + rg * 16 + c);
    #pragma unroll
    for (int nt = 0; nt < 6; ++nt) {
      floatx4 bia = *(const floatx4*)(b2 + nt * 16 + q * 4);
      half4 yy;
      #pragma unroll
      for (int r = 0; r < 4; ++r)
        yy[r] = (_Float16)((acc2[rg][nt][r] + bia[r]) * sg[rg]);
      *(half4*)(Yc + row * 96 + nt * 16 + q * 4) = yy;
    }
  }
}

// one ht-step of the var MLP, rg=2, operands from LDS
#define VSTEPL(HTG, HTS)                                                                 \
  {                                                                                      \
    half8 wa0 = wb[((HTS) * 2 + 0) * 64 + l];                                            \
    half8 wa1 = wb[((HTS) * 2 + 1) * 64 + l];                                            \
    half8 wp0 = wb[256 + ((HTS) * 2 + 0) * 64 + l];                                      \
    half8 wp1 = wb[256 + ((HTS) * 2 + 1) * 64 + l];                                      \
    floatx4 i0 = *(const floatx4*)&b1L[(HTG) * 16 + q * 4];                              \
    floatx4 a0 = i0, a1 = i0;                                                            \
    a0 = __builtin_amdgcn_mfma_f32_16x16x32_f16(wa0, mb[0][0], a0, 0, 0, 0);             \
    a1 = __builtin_amdgcn_mfma_f32_16x16x32_f16(wa0, mb[1][0], a1, 0, 0, 0);             \
    a0 = __builtin_amdgcn_mfma_f32_16x16x32_f16(wa1, mb[0][1], a0, 0, 0, 0);             \
    a1 = __builtin_amdgcn_mfma_f32_16x16x32_f16(wa1, mb[1][1], a1, 0, 0, 0);             \
    half4 h0, h1;                                                                        \
    _Pragma("unroll")                                                                    \
    for (int r = 0; r < 4; ++r) h0[r] = (_Float16)gelu_lut(tab, a0[r]);                  \
    _Pragma("unroll")                                                                    \
    for (int r = 0; r < 4; ++r) h1[r] = (_Float16)gelu_lut(tab, a1[r]);                  \
    acc2[0][0] = __builtin_amdgcn_mfma_f32_16x16x16f16(lo4(wp0), h0, acc2[0][0], 0,0,0); \
    acc2[1][0] = __builtin_amdgcn_mfma_f32_16x16x16f16(lo4(wp0), h1, acc2[1][0], 0,0,0); \
    acc2[0][1] = __builtin_amdgcn_mfma_f32_16x16x16f16(hi4(wp0), h0, acc2[0][1], 0,0,0); \
    acc2[1][1] = __builtin_amdgcn_mfma_f32_16x16x16f16(hi4(wp0), h1, acc2[1][1], 0,0,0); \
    acc2[0][2] = __builtin_amdgcn_mfma_f32_16x16x16f16(lo4(wp1), h0, acc2[0][2], 0,0,0); \
    acc2[1][2] = __builtin_amdgcn_mfma_f32_16x16x16f16(lo4(wp1), h1, acc2[1][2], 0,0,0); \
    acc2[0][3] = __builtin_amdgcn_mfma_f32_16x16x16f16(hi4(wp1), h0, acc2[0][3], 0,0,0); \
    acc2[1][3] = __builtin_amdgcn_mfma_f32_16x16x16f16(hi4(wp1), h1, acc2[1][3], 0,0,0); \
  }

// wave w DMA-stages its 2 of 8 segments of chunk CH (256 w1v + 256 w2v
// entries, 4096 B each array).
#define VSTAGE(CH, BUF)                                                      \
  {                                                                          \
    if (w < 2) {                                                             \
      const char* gsrc = (const char*)W1p + (size_t)(CH) * 4096;             \
      _Pragma("unroll")                                                      \
      for (int s_ = 0; s_ < 2; ++s_)                                         \
        gload_lds16(gsrc + (((w * 2 + s_) * 64 + l) << 4),                   \
                    &wbuf[BUF][(w * 2 + s_) * 64]);                          \
    } else {                                                                 \
      const char* gsrc = (const char*)W2p + (size_t)(CH) * 4096;             \
      _Pragma("unroll")                                                      \
      for (int s_ = 0; s_ < 2; ++s_)                                         \
        gload_lds16(gsrc + ((((w - 2) * 2 + s_) * 64 + l) << 4),             \
                    &wbuf[BUF][(4 + (w - 2) * 2 + s_) * 64]);                \
    }                                                                        \
  }

// Variable-node MLP, 32 vars/wave, 128 vars/block, DMA chunk staging
// (7 chunks of 2 ht; tile 13 is exact-zero padding).
__global__ __launch_bounds__(256, 4) void kernelV(
    const _Float16* __restrict__ Yc, const int* __restrict__ perm,
    const float* __restrict__ prior,
    _Float16* __restrict__ Mc, float* __restrict__ outp,
    const _Float16* __restrict__ W1p, const _Float16* __restrict__ W2p,
    const float* __restrict__ b1, const float* __restrict__ b2)
{
  __shared__ float2 tab[1024];                               // 8 KB
  __shared__ __attribute__((aligned(16))) float b1L[224];    // 0.9 KB
  __shared__ half8 wbuf[2][512];                             // 2 x 8 KB chunks

  const int tid = threadIdx.x, w = tid >> 6, l = tid & 63;
  const int q = l >> 4, c = l & 15;
  const int r0 = blockIdx.x * 128 + w * 32;
  const int b  = r0 >> 10;
  const int v0 = r0 & 1023;
  const size_t yb = (size_t)b * EDGE;

  VSTAGE(0, 0)

  for (int k_ = tid; k_ < 1024; k_ += 256) {
    float x_  = (k_ - 512) * 0.015625f;
    float y0_ = gelu_f(x_);
    float y1_ = gelu_f(x_ + 0.015625f);
    tab[k_] = make_float2(y0_, y1_ - y0_);
  }
  if (tid < 224) b1L[tid] = b1[tid];

  // Xv^T fragments: lane holds var-row n = l&15, k = q*8+j
  half8 mb[2][2];
  #pragma unroll
  for (int rg = 0; rg < 2; ++rg) {
    int v = v0 + rg * 16 + c;
    int e0 = perm[3 * v + (q >> 1)];
    mb[rg][0] = *(const half8*)(Yc + (yb + e0) * 16 + (q & 1) * 8);
    half8 m1 = {0,0,0,0,0,0,0,0};
    if (q < 2) {
      int e2 = perm[3 * v + 2];
      m1 = *(const half8*)(Yc + (yb + e2) * 16 + q * 8);
    } else if (q == 2) {
      m1[0] = (_Float16)prior[v];
    }
    mb[rg][1] = m1;
  }

  floatx4 acc2[2][4];
  #pragma unroll
  for (int rg = 0; rg < 2; ++rg)
    #pragma unroll
    for (int nt = 0; nt < 4; ++nt)
      acc2[rg][nt] = (floatx4){0.f, 0.f, 0.f, 0.f};

  __syncthreads();

  int cur = 0;
  #pragma unroll 1
  for (int i = 0; i < 7; ++i) {
    if (i < 6) VSTAGE(i + 1, cur ^ 1)
    const half8* wb = (const half8*)wbuf[cur];
    VSTEPL(2 * i,     0)
    VSTEPL(2 * i + 1, 1)
    if (i < 6) {
      __syncthreads();
      cur ^= 1;
    }
  }

  const float bllr = b2[48];
  #pragma unroll
  for (int rg = 0; rg < 2; ++rg) {
    int v = v0 + rg * 16 + c;
    #pragma unroll
    for (int nt = 0; nt < 3; ++nt) {
      int pe = perm[3 * v + nt];
      floatx4 bia = *(const floatx4*)(b2 + nt * 16 + q * 4);
      half4 yy;
      #pragma unroll
      for (int r = 0; r < 4; ++r)
        yy[r] = (_Float16)(acc2[rg][nt][r] + bia[r]);
      *(half4*)(Mc + (yb + pe) * 16 + q * 4) = yy;
    }
    if (q == 0)
      outp[r0 + rg * 16 + c] = acc2[rg][3][0] + bllr;
  }
}

extern "C" void kernel_launch(void* const* d_in, const int* in_sizes, int n_in,
                              void* d_out, int out_size, void* d_ws, size_t ws_size,
                              hipStream_t stream)
{
  const int*   synd  = (const int*)d_in[0];
  const float* prior = (const float*)d_in[2];
  const int*   perm  = (const int*)d_in[3];
  const float* cW1 = (const float*)d_in[4];
  const float* cb1 = (const float*)d_in[5];
  const float* cW2 = (const float*)d_in[6];
  const float* cb2 = (const float*)d_in[7];
  const float* vW1 = (const float*)d_in[8];
  const float* vb1 = (const float*)d_in[9];
  const float* vW2 = (const float*)d_in[10];
  const float* vb2 = (const float*)d_in[11];
  float* outp = (float*)d_out;
  const int T = out_size / (BATCH * NVAR);

  char* p = (char*)d_ws;
  _Float16* Mc  = (_Float16*)p; p += (size_t)BATCH * EDGE * 16 * 2;
  _Float16* Yc  = (_Float16*)p; p += (size_t)BATCH * EDGE * 16 * 2;
  _Float16* w1c = (_Float16*)p; p += (size_t)NT1C * 3 * 64 * 8 * 2;
  _Float16* w2c = (_Float16*)p; p += (size_t)NT1C * 3 * 64 * 8 * 2;
  _Float16* w1v = (_Float16*)p; p += (size_t)NT1VP * 2 * 64 * 8 * 2;
  _Float16* w2v = (_Float16*)p; p += (size_t)NT1VP * 2 * 64 * 8 * 2;
  float* bwp  = (float*)p; p += 416 * 4;
  float* bwm  = (float*)p; p += 416 * 4;
  float* b2c  = (float*)p; p += 96 * 4;
  float* b1v  = (float*)p; p += 224 * 4;
  float* b2v  = (float*)p; p += 64 * 4;

  const int packN = NT1C * 3 * 64 * 2 + NT1VP * 2 * 64 * 2 +
                    416 + 416 + 96 + 224 + 64;   // 14784
  pack_kernel<<<(packN + 255) / 256, 256, 0, stream>>>(
      cW1, cb1, cW2, cb2, vW1, vb1, vW2, vb2,
      w1c, w2c, w1v, w2v, bwp, bwm, b2c, b1v, b2v);
  init_kernel<<<(BATCH * EDGE) / 256, 256, 0, stream>>>(perm, prior, Mc);

  for (int t = 0; t < T; ++t) {
    kernelC<<<(BATCH * NCHK) / 128, 256, 0, stream>>>(
        Mc, synd, Yc, w1c, w2c, bwp, bwm, b2c);
    kernelV<<<(BATCH * NVAR) / 128, 256, 0, stream>>>(
        Yc, perm, prior, Mc, outp + (size_t)t * BATCH * NVAR, w1v, w2v, b1v, b2v);
  }
}